// Round 5
// baseline (325.067 us; speedup 1.0000x reference)
//
#include <hip/hip_runtime.h>
#include <stdint.h>

// Problem constants
#define BB 4
#define SS 2048
#define PP 8
#define FIN 1024
#define FOUT 1024
#define MROWS (BB*SS)          // 8192 rows per group
#define ROWSTRIDE (PP*FIN)     // 8192 floats between consecutive (b,s) rows
#define OROWSTRIDE (PP*FOUT)

// Tile config: 256(m) x 128(n), BK=64, 512 threads (8 waves as 4m x 2n)
#define BM 256
#define BN 128
#define BK 64
#define NKT (FIN/BK)           // 16 K-tiles

typedef float fx4 __attribute__((ext_vector_type(4)));
typedef short sv8 __attribute__((ext_vector_type(8)));   // 8 bf16 (MFMA frag)

union BCvt { sv8 s; __bf16 b[8]; };

__device__ __forceinline__ unsigned short bfbits(float f) {
    union { __bf16 b; unsigned short u; } c; c.b = (__bf16)f; return c.u;
}
__device__ __forceinline__ sv8 cvt8(fx4 lo, fx4 hi) {
    BCvt u;
#pragma unroll
    for (int i = 0; i < 4; ++i) { u.b[i] = (__bf16)lo[i]; u.b[i + 4] = (__bf16)hi[i]; }
    return u.s;
}

// ---------------------------------------------------------------------------
// Prepass: W [P][K][N] fp32 -> Wt tiled+swizzled bf16 (16.8 MB in d_ws).
// Tile (p, nt, kt) = contiguous 16 KB LDS image of B[128 n][64 k]:
//   byte_in_tile = n*128 + ((kg*16) ^ ((n&7)<<4)), kg = k/8
// n-halves of 64 rows are each 8 KB contiguous.
// ---------------------------------------------------------------------------
__global__ __launch_bounds__(256) void wtrans(const float* __restrict__ w,
                                              unsigned short* __restrict__ wt) {
    __shared__ unsigned short L[64][132];
    const int bid = blockIdx.x;              // 8*8*16 = 1024 blocks
    const int p  = bid >> 7;
    const int nt = (bid >> 4) & 7;
    const int kt = bid & 15;
    const int k0 = kt * 64, n0 = nt * 128;
    const int t = threadIdx.x;

    const int nf = t & 31, kl = t >> 5;
#pragma unroll
    for (int rr = 0; rr < 8; ++rr) {
        const int k = rr * 8 + kl;
        fx4 v = *(const fx4*)(w + (size_t)p * (FIN*FOUT) + (size_t)(k0 + k) * FOUT + n0 + nf * 4);
        L[k][nf*4+0] = bfbits(v[0]); L[k][nf*4+1] = bfbits(v[1]);
        L[k][nf*4+2] = bfbits(v[2]); L[k][nf*4+3] = bfbits(v[3]);
    }
    __syncthreads();

    unsigned short* tile = wt + (size_t)bid * 8192;   // (p*8+nt)*16+kt ordering
    const int n = t & 127, khalf = t >> 7;
#pragma unroll
    for (int rr = 0; rr < 4; ++rr) {
        const int kg = khalf * 4 + rr;
        union { sv8 s; unsigned short us[8]; } u;
#pragma unroll
        for (int e = 0; e < 8; ++e) u.us[e] = L[kg * 8 + e][n];
        const int byte_ = n * 128 + ((kg * 16) ^ ((n & 7) << 4));
        *(sv8*)((char*)tile + byte_) = u.s;
    }
}

// ---------------------------------------------------------------------------
// 256x128 grouped GEMM. A reg-staged 2-ahead (fp32->bf16), B 3-deep
// global_load_lds ring, counted vmcnt(10) ledger, 4 phases/K-tile.
// ---------------------------------------------------------------------------
#define STR2(x) #x
#define VMBAR(N) do {                                                          \
    asm volatile("s_waitcnt vmcnt(" STR2(N) ") lgkmcnt(0)" ::: "memory");      \
    __builtin_amdgcn_s_barrier();                                              \
} while (0)
#define LGKBAR do {                                                            \
    asm volatile("s_waitcnt lgkmcnt(0)" ::: "memory");                         \
    __builtin_amdgcn_s_barrier();                                              \
} while (0)
#define BAR __builtin_amdgcn_s_barrier()

// A half (128 rows): thread (arow = tid>>2, akq = tid&3): 16 contiguous fp32
#define LOADA_HALF(kt, h, r) do {                                              \
    const float* s_ = x + (size_t)(m0 + (h) * 128 + arow) * ROWSTRIDE          \
                        + p * FIN + (kt) * BK + akq * 16;                      \
    r[0] = *(const fx4*)s_;       r[1] = *(const fx4*)(s_ + 4);                \
    r[2] = *(const fx4*)(s_ + 8); r[3] = *(const fx4*)(s_ + 12);               \
} while (0)

// cvt + 2 x ds_write_b128 into swizzled 16 KB half image
#define STOREA_HALF(dst, r) do {                                               \
    const int sw_ = (arow & 7) << 4;                                           \
    char* bp_ = (dst) + arow * 128;                                            \
    *(sv8*)(bp_ + (((akq * 2) * 16)     ^ sw_)) = cvt8(r[0], r[1]);            \
    *(sv8*)(bp_ + (((akq * 2 + 1) * 16) ^ sw_)) = cvt8(r[2], r[3]);            \
} while (0)

// B half: 8 KB via 1 x global_load_lds width-16 (pre-swizzled source)
#define GLOADB_HALF(kt, dstbase, h) do {                                       \
    __builtin_amdgcn_global_load_lds(                                          \
        (const __attribute__((address_space(1))) void*)((const char*)btile     \
            + (size_t)(kt) * 16384 + (h) * 8192 + tid * 16),                   \
        (__attribute__((address_space(3))) void*)((dstbase) + (h) * 8192 + tid * 16), \
        16, 0, 0);                                                             \
} while (0)

// wave rows: wm (0..3) -> half (wm>>1), local 64-block (wm&1); mh = 32-row sub
#define READ_A(AcBase, mh) do {                                                \
    const char* hb_ = (AcBase) + (wm >> 1) * 16384;                            \
    _Pragma("unroll")                                                          \
    for (int fi = 0; fi < 2; ++fi) {                                           \
        const int row_ = (wm & 1) * 64 + (mh) * 32 + fi * 16 + (lane & 15);    \
        const char* bp_ = hb_ + row_ * 128;                                    \
        const int sw_ = (row_ & 7) << 4;                                       \
        _Pragma("unroll")                                                      \
        for (int ks = 0; ks < 2; ++ks)                                         \
            af[fi][ks] = *(const sv8*)(bp_ + ((ks * 64 + (lane >> 4) * 16) ^ sw_)); \
    }                                                                          \
} while (0)

#define READ_B(Bc, nh, dst) do {                                               \
    _Pragma("unroll")                                                          \
    for (int j = 0; j < 2; ++j) {                                              \
        const int row_ = wn * 64 + (nh) * 32 + j * 16 + (lane & 15);           \
        const char* bp_ = (Bc) + row_ * 128;                                   \
        const int sw_ = (row_ & 7) << 4;                                       \
        _Pragma("unroll")                                                      \
        for (int ks = 0; ks < 2; ++ks)                                         \
            dst[j][ks] = *(const sv8*)(bp_ + ((ks * 64 + (lane >> 4) * 16) ^ sw_)); \
    }                                                                          \
} while (0)

#define MFMA_Q(mh, nh, bfr) do {                                               \
    __builtin_amdgcn_s_setprio(1);                                             \
    _Pragma("unroll")                                                          \
    for (int fi = 0; fi < 2; ++fi)                                             \
        _Pragma("unroll")                                                      \
        for (int j = 0; j < 2; ++j)                                            \
            _Pragma("unroll")                                                  \
            for (int ks = 0; ks < 2; ++ks)                                     \
                acc[(mh)*2+fi][(nh)*2+j] = __builtin_amdgcn_mfma_f32_16x16x32_bf16( \
                    af[fi][ks], bfr[j][ks], acc[(mh)*2+fi][(nh)*2+j], 0, 0, 0);\
    __builtin_amdgcn_s_setprio(0);                                             \
} while (0)

// Ledger (entry invariant: B(t+1) 2 + A(t+1) 8 = 10 outstanding):
//  p0: +1 B(t+2)h0; p1: +1 B(t+2)h1; p2: STOREA h0 (compiler waits A(t+1)h0,
//  retiring B(t+1) as older), +4 A(t+2)h0; p3: STOREA h1, +4 A(t+2)h1;
//  VMBAR(10) leaves exactly B(t+2)2 + A(t+2)8. Invariant restored.
#define TILE_BODY(t, Ac, An, Bc, B2, PREF) do {                                \
    /* phase 0 */                                                              \
    READ_A((Ac), 0); READ_B((Bc), 0, bf0);                                     \
    if (PREF) GLOADB_HALF((t) + 2, (B2), 0);                                   \
    BAR; MFMA_Q(0, 0, bf0); BAR;                                               \
    /* phase 1 */                                                              \
    READ_B((Bc), 1, bf1);                                                      \
    if (PREF) GLOADB_HALF((t) + 2, (B2), 1);                                   \
    BAR; MFMA_Q(0, 1, bf1); BAR;                                               \
    /* phase 2 */                                                              \
    READ_A((Ac), 1);                                                           \
    if ((t) <= 14) STOREA_HALF((An), rA0);                                     \
    if (PREF) LOADA_HALF((t) + 2, 0, rA0);                                     \
    BAR; MFMA_Q(1, 1, bf1); BAR;                                               \
    /* phase 3 */                                                              \
    if ((t) <= 14) STOREA_HALF((An) + 16384, rA1);                             \
    if (PREF) LOADA_HALF((t) + 2, 1, rA1);                                     \
    if (PREF)           VMBAR(10);                                             \
    else if ((t) == 14) VMBAR(0);                                              \
    else                LGKBAR;                                                \
    MFMA_Q(1, 0, bf0); BAR;                                                    \
} while (0)

__global__ __launch_bounds__(512, 1)
void pd_gemm(const float* __restrict__ x, const unsigned short* __restrict__ wt,
             const float* __restrict__ bias, float* __restrict__ out) {
    __shared__ __align__(16) char ldsA[2 * 2 * 16384];   // [dbuf][half] 64 KB
    __shared__ __align__(16) char ldsB[3 * 16384];       // 3-ring, 48 KB

    const int tid = threadIdx.x;
    const int lane = tid & 63;
    const int wv = tid >> 6;            // 8 waves: 4(m) x 2(n)
    const int wm = wv >> 1, wn = wv & 1;

    // p == XCD (bid%8); within XCD: n fastest (8 sharers of an m-panel are
    // co-resident on one XCD -> 4 fp32 m-panels = 4 MB = L2-resident)
    const int bid = blockIdx.x;
    const int p   = bid & 7;
    const int wrk = bid >> 3;           // 0..255
    const int n0  = (wrk & 7) * BN;
    const int m0  = (wrk >> 3) * BM;

    const int arow = tid >> 2, akq = tid & 3;   // A staging map
    const unsigned short* btile = wt + (size_t)((p * 8 + (n0 >> 7)) * 16) * 8192;

    fx4 acc[4][4];
#pragma unroll
    for (int i = 0; i < 4; ++i)
#pragma unroll
        for (int j = 0; j < 4; ++j) acc[i][j] = (fx4)0.0f;

    fx4 rA0[4], rA1[4];
    sv8 af[2][2], bf0[2][2], bf1[2][2];

    // Prologue: establish invariant (B(1) 2 + A(1) 8 = 10 outstanding)
    LOADA_HALF(0, 0, rA0); LOADA_HALF(0, 1, rA1);          // 8
    GLOADB_HALF(0, ldsB, 0); GLOADB_HALF(0, ldsB, 1);      // +2
    GLOADB_HALF(1, ldsB + 16384, 0); GLOADB_HALF(1, ldsB + 16384, 1); // +2
    STOREA_HALF(ldsA, rA0); STOREA_HALF(ldsA + 16384, rA1); // waits A(0)
    LOADA_HALF(1, 0, rA0); LOADA_HALF(1, 1, rA1);          // +8 -> 12
    VMBAR(10);   // retire B(0); leave B(1)2 + A(1)8

    char* b0 = ldsB;              // ring: cur
    char* b1 = ldsB + 16384;      // t+1
    char* b2 = ldsB + 32768;      // t+2 dest
#pragma unroll 1
    for (int t = 0; t < 14; ++t) {
        char* Ac = ldsA + (t & 1) * 32768;
        char* An = ldsA + ((t + 1) & 1) * 32768;
        TILE_BODY(t, Ac, An, b0, b2, true);
        char* tmp = b0; b0 = b1; b1 = b2; b2 = tmp;
    }
    TILE_BODY(14, ldsA, ldsA + 32768, b0, b2, false);
    TILE_BODY(15, ldsA + 32768, ldsA, b1, b2, false);

    // Epilogue: C/D map col = lane&15, row = (lane>>4)*4 + j
    const float* bs = bias + p * FOUT;
#pragma unroll
    for (int nf = 0; nf < 4; ++nf) {
        const int col = n0 + wn * 64 + nf * 16 + (lane & 15);
        const float bv = bs[col];
#pragma unroll
        for (int mf = 0; mf < 4; ++mf) {
            const int row = m0 + wm * 64 + mf * 16 + (lane >> 4) * 4;
            float* o = out + (size_t)row * OROWSTRIDE + p * FOUT + col;
#pragma unroll
            for (int j = 0; j < 4; ++j)
                o[j * OROWSTRIDE] = acc[mf][nf][j] + bv;
        }
    }
}

// Fallback if d_ws can't hold Wt (never observed): correct but slow.
__global__ __launch_bounds__(256) void pd_naive(const float* __restrict__ x,
                                                const float* __restrict__ w,
                                                const float* __restrict__ bias,
                                                float* __restrict__ out) {
    const long long total = (long long)MROWS * PP * FOUT;
    for (long long idx = blockIdx.x * 256LL + threadIdx.x; idx < total;
         idx += (long long)gridDim.x * 256) {
        const int n = (int)(idx & 1023);
        const int p = (int)((idx >> 10) & 7);
        const long long m = idx >> 13;
        const float* xr = x + m * ROWSTRIDE + p * FIN;
        const float* wc = w + (size_t)p * (FIN*FOUT) + n;
        float s = bias[p * FOUT + n];
        for (int k = 0; k < FIN; ++k) s += xr[k] * wc[(size_t)k * FOUT];
        out[idx] = s;
    }
}

extern "C" void kernel_launch(void* const* d_in, const int* in_sizes, int n_in,
                              void* d_out, int out_size, void* d_ws, size_t ws_size,
                              hipStream_t stream) {
    const float* x    = (const float*)d_in[0];
    const float* w    = (const float*)d_in[1];
    const float* bias = (const float*)d_in[2];
    float* out = (float*)d_out;

    const size_t WT_BYTES = (size_t)PP * FIN * FOUT * sizeof(unsigned short);  // 16.8 MB
    if (ws_size >= WT_BYTES) {
        unsigned short* wt = (unsigned short*)d_ws;
        wtrans<<<dim3(1024), dim3(256), 0, stream>>>(w, wt);
        const int nblk = PP * (MROWS / BM) * (FOUT / BN);   // 8*32*8 = 2048
        pd_gemm<<<dim3(nblk), dim3(512), 0, stream>>>(x, wt, bias, out);
    } else {
        pd_naive<<<dim3(2048), dim3(256), 0, stream>>>(x, w, bias, out);
    }
}

// Round 7
// 306.188 us; speedup vs baseline: 1.0617x; 1.0617x over previous
//
#include <hip/hip_runtime.h>
#include <stdint.h>

// Problem constants
#define PP 8
#define FIN 1024
#define FOUT 1024
#define MROWS 8192
#define ROWSTRIDE 8192         // floats between consecutive (b,s) rows
#define OROWSTRIDE 8192

// Tile config: 256(m) x 128(n), BK=64, 512 threads (8 waves as 4m x 2n)
#define BM 256
#define BN 128
#define NKT 16

typedef float fx4 __attribute__((ext_vector_type(4)));
typedef short sv8 __attribute__((ext_vector_type(8)));   // 8 bf16 (MFMA frag)
typedef short sv4 __attribute__((ext_vector_type(4)));

union BCvt  { sv8 s; __bf16 b[8]; };
union BCvt4 { sv4 s; __bf16 b[4]; };

__device__ __forceinline__ unsigned short bfbits(float f) {
    union { __bf16 b; unsigned short u; } c; c.b = (__bf16)f; return c.u;
}

// ---------------------------------------------------------------------------
// Swizzled tile image (A and B identical format): per 64-k tile,
//   byte = row*128 + ((kg*16) ^ ((row&7)<<4)),  kg = k/8  (8 bf16 per slot)
// Staged verbatim by linear global_load_lds; read with the same XOR.
// ---------------------------------------------------------------------------

// Prepass 1 (verified in round 5): W [P][K][N] fp32 -> Wt 16 KB tiles
// (p, nt128, kt) at index ((p*8+nt)*16+kt)*8192 shorts.
__global__ __launch_bounds__(256) void wtrans(const float* __restrict__ w,
                                              unsigned short* __restrict__ wt) {
    __shared__ unsigned short L[64][132];
    const int bid = blockIdx.x;              // 8*8*16 = 1024
    const int p  = bid >> 7;
    const int nt = (bid >> 4) & 7;
    const int kt = bid & 15;
    const int k0 = kt * 64, n0 = nt * 128;
    const int t = threadIdx.x;

    const int nf = t & 31, kl = t >> 5;
#pragma unroll
    for (int rr = 0; rr < 8; ++rr) {
        const int k = rr * 8 + kl;
        fx4 v = *(const fx4*)(w + (size_t)p * (FIN*FOUT) + (size_t)(k0 + k) * FOUT + n0 + nf * 4);
        L[k][nf*4+0] = bfbits(v[0]); L[k][nf*4+1] = bfbits(v[1]);
        L[k][nf*4+2] = bfbits(v[2]); L[k][nf*4+3] = bfbits(v[3]);
    }
    __syncthreads();

    unsigned short* tile = wt + (size_t)bid * 8192;
    const int n = t & 127, khalf = t >> 7;
#pragma unroll
    for (int rr = 0; rr < 4; ++rr) {
        const int kg = khalf * 4 + rr;
        union { sv8 s; unsigned short us[8]; } u;
#pragma unroll
        for (int e = 0; e < 8; ++e) u.us[e] = L[kg * 8 + e][n];
        const int byte_ = n * 128 + ((kg * 16) ^ ((n & 7) << 4));
        *(sv8*)((char*)tile + byte_) = u.s;
    }
}

// Prepass 2: x fp32 -> xt 32 KB tiles (p, mt256, kt) at ((p*MT+mt)*16+kt).
// Coalesced: one WAVE per row-round, lane l reads 16 B at src + rnd*1KB + l*16.
// lane l holds k0 = rnd*256 + l*4 (4 floats) -> 8 B swizzled store:
//   kt = rnd*4 + (l>>4); kg = (l&15)>>1; byte-in-slot = (l&1)*8.
__global__ __launch_bounds__(256) void xcvt(const float* __restrict__ x,
                                            unsigned short* __restrict__ xt,
                                            int m_base, int MT) {
    const int bid = blockIdx.x;          // 8 * MT * 4
    const int p   = bid & 7;
    const int q   = bid >> 3;
    const int mt  = q >> 2;
    const int seg = q & 3;
    const int w   = threadIdx.x >> 6;
    const int l   = threadIdx.x & 63;

    char* tiles = (char*)xt + (size_t)((p * MT + mt) * 16) * 32768;
    const int ktl = l >> 4;
    const int kg  = (l & 15) >> 1;
    const int e8  = (l & 1) * 8;

#pragma unroll 2
    for (int i = 0; i < 16; ++i) {
        const int r = seg * 64 + w * 16 + i;
        const float* src = x + (size_t)(m_base + mt * 256 + r) * ROWSTRIDE + p * FIN;
        char* rowdst = tiles + r * 128 + ((kg * 16) ^ ((r & 7) << 4)) + e8;
#pragma unroll
        for (int rnd = 0; rnd < 4; ++rnd) {
            fx4 v = *(const fx4*)(src + rnd * 256 + l * 4);
            BCvt4 u;
            u.b[0] = (__bf16)v[0]; u.b[1] = (__bf16)v[1];
            u.b[2] = (__bf16)v[2]; u.b[3] = (__bf16)v[3];
            *(sv4*)(rowdst + (size_t)(rnd * 4 + ktl) * 32768) = u.s;
        }
    }
}

// ---------------------------------------------------------------------------
// Triple-buffered pure-gload GEMM. Tile t reads buf t%3; tile t+2 stages
// into buf (t+2)%3 (never live). One vmcnt(6)+barrier per K-tile.
// ---------------------------------------------------------------------------
#define STR2(x) #x
#define VMC(N) asm volatile("s_waitcnt vmcnt(" STR2(N) ")" ::: "memory")
#define BARX do { asm volatile("" ::: "memory"); __builtin_amdgcn_s_barrier(); \
                  asm volatile("" ::: "memory"); } while (0)

// A: 32 KB tile = 4 gloads (512 thr x 16 B = 8 KB each), as two 16 KB halves
#define GLA(skt, h, As) do {                                                   \
    const char* s_ = apanel + (size_t)(skt) * 32768 + (h) * 16384 + tid * 16;  \
    char* d_ = (As) + (h) * 16384 + tid * 16;                                  \
    __builtin_amdgcn_global_load_lds(                                          \
        (const __attribute__((address_space(1))) void*)s_,                     \
        (__attribute__((address_space(3))) void*)d_, 16, 0, 0);                \
    __builtin_amdgcn_global_load_lds(                                          \
        (const __attribute__((address_space(1))) void*)(s_ + 8192),            \
        (__attribute__((address_space(3))) void*)(d_ + 8192), 16, 0, 0);       \
} while (0)

// B: 16 KB tile = 2 gloads
#define GLB(skt, Bs) do {                                                      \
    const char* s_ = btile + (size_t)(skt) * 16384 + tid * 16;                 \
    char* d_ = (Bs) + tid * 16;                                                \
    __builtin_amdgcn_global_load_lds(                                          \
        (const __attribute__((address_space(1))) void*)s_,                     \
        (__attribute__((address_space(3))) void*)d_, 16, 0, 0);                \
    __builtin_amdgcn_global_load_lds(                                          \
        (const __attribute__((address_space(1))) void*)(s_ + 8192),            \
        (__attribute__((address_space(3))) void*)(d_ + 8192), 16, 0, 0);       \
} while (0)

// read 2x2 frags: local rows lr0 + {0,16} + lane&15, k-halves ks*32
#define RD4(baseptr, lr0, dst) do {                                            \
    _Pragma("unroll")                                                          \
    for (int fi_ = 0; fi_ < 2; ++fi_) {                                        \
        const int row_ = (lr0) + fi_ * 16 + (lane & 15);                       \
        const char* bp_ = (baseptr) + row_ * 128;                              \
        const int sw_ = (row_ & 7) << 4;                                       \
        _Pragma("unroll")                                                      \
        for (int ks_ = 0; ks_ < 2; ++ks_)                                      \
            dst[fi_][ks_] = *(const sv8*)(bp_ + ((ks_ * 64 + (lane >> 4) * 16) ^ sw_)); \
    }                                                                          \
} while (0)

#define MQ(mh, nh, aF, bF) do {                                                \
    __builtin_amdgcn_s_setprio(1);                                             \
    _Pragma("unroll")                                                          \
    for (int fi_ = 0; fi_ < 2; ++fi_)                                          \
        _Pragma("unroll")                                                      \
        for (int j_ = 0; j_ < 2; ++j_)                                         \
            _Pragma("unroll")                                                  \
            for (int ks_ = 0; ks_ < 2; ++ks_)                                  \
                acc[(mh)*2+fi_][(nh)*2+j_] = __builtin_amdgcn_mfma_f32_16x16x32_bf16( \
                    aF[fi_][ks_], bF[j_][ks_], acc[(mh)*2+fi_][(nh)*2+j_], 0, 0, 0); \
    __builtin_amdgcn_s_setprio(0);                                             \
} while (0)

// ENDW: 2 = vmcnt(6)+bar (steady), 1 = vmcnt(0)+bar (t=14), 0 = none (t=15)
#define TILE(Ar, Br, As, Bs, skt, STAGE, ENDW) do {                            \
    const char* Aw_ = (Ar) + wm * 8192;                                        \
    const char* Bw_ = (Br) + wn * 8192;                                        \
    RD4(Aw_, 0, af0); RD4(Bw_, 0, bf0);                                        \
    if (STAGE) GLA(skt, 0, As);                                                \
    MQ(0, 0, af0, bf0);                                                        \
    RD4(Bw_, 32, bf1);                                                         \
    if (STAGE) GLA(skt, 1, As);                                                \
    MQ(0, 1, af0, bf1);                                                        \
    RD4(Aw_, 32, af1);                                                         \
    if (STAGE) GLB(skt, Bs);                                                   \
    MQ(1, 1, af1, bf1);                                                        \
    MQ(1, 0, af1, bf0);                                                        \
    if ((ENDW) == 2) { VMC(6); BARX; }                                         \
    else if ((ENDW) == 1) { VMC(0); BARX; }                                    \
} while (0)

__global__ __launch_bounds__(512, 1)
void pd_gemm(const unsigned short* __restrict__ xt, const unsigned short* __restrict__ wtb,
             const float* __restrict__ bias, float* __restrict__ out,
             int m_base, int MT) {
    __shared__ __align__(16) char A0[32768];
    __shared__ __align__(16) char A1[32768];
    __shared__ __align__(16) char A2[32768];
    __shared__ __align__(16) char B0[16384];
    __shared__ __align__(16) char B1[16384];
    __shared__ __align__(16) char B2[16384];

    const int tid = threadIdx.x;
    const int lane = tid & 63;
    const int wv = tid >> 6;            // 8 waves: 4(m) x 2(n)
    const int wm = wv >> 1, wn = wv & 1;

    // p == XCD; within p: n fastest (8 n-sharers of an A-panel co-resident)
    const int bid = blockIdx.x;
    const int p   = bid & 7;
    const int q   = bid >> 3;
    const int nt  = q & 7;
    const int mt  = q >> 3;
    const int n0  = nt * 128;

    const char* apanel = (const char*)xt  + (size_t)((p * MT + mt) * 16) * 32768;
    const char* btile  = (const char*)wtb + (size_t)((p * 8 + nt) * 16) * 16384;

    fx4 acc[4][4];
#pragma unroll
    for (int i = 0; i < 4; ++i)
#pragma unroll
        for (int j = 0; j < 4; ++j) acc[i][j] = (fx4)0.0f;

    sv8 af0[2][2], af1[2][2], bf0[2][2], bf1[2][2];

    // Prologue: tile0 -> buf0 (6 loads), tile1 -> buf1 (6 loads).
    GLA(0, 0, A0); GLA(0, 1, A0); GLB(0, B0);
    GLA(1, 0, A1); GLA(1, 1, A1); GLB(1, B1);
    VMC(6);     // retire tile0's 6; tile1's 6 stay in flight
    BARX;

    // Steady state: tile t reads buf t%3, stages tile t+2 into buf (t+2)%3.
    // Ledger: entry 6 (tile t+1) + 6 issued (tile t+2) -> vmcnt(6) retires
    // tile t+1's, leaving tile t+2's. Full K-tile of latency cover per load.
#pragma unroll 1
    for (int tb = 0; tb < 12; tb += 3) {
        TILE(A0, B0, A2, B2, tb + 2, 1, 2);
        TILE(A1, B1, A0, B0, tb + 3, 1, 2);
        TILE(A2, B2, A1, B1, tb + 4, 1, 2);
    }
    TILE(A0, B0, A2, B2, 14, 1, 2);     // t=12
    TILE(A1, B1, A0, B0, 15, 1, 2);     // t=13
    TILE(A2, B2, A0, B0,  0, 0, 1);     // t=14: vmcnt(0) -> tile15 landed
    TILE(A0, B0, A1, B1,  0, 0, 0);     // t=15

    // Epilogue: C/D map col = lane&15, row = (lane>>4)*4 + j (verified r1-5)
    const float* bs = bias + p * FOUT;
#pragma unroll
    for (int nf = 0; nf < 4; ++nf) {
        const int col = n0 + wn * 64 + nf * 16 + (lane & 15);
        const float bv = bs[col];
#pragma unroll
        for (int mf = 0; mf < 4; ++mf) {
            const int row = m_base + mt * 256 + wm * 64 + mf * 16 + (lane >> 4) * 4;
            float* o = out + (size_t)row * OROWSTRIDE + p * FOUT + col;
#pragma unroll
            for (int j = 0; j < 4; ++j)
                o[j * OROWSTRIDE] = acc[mf][nf][j] + bv;
        }
    }
}

// Fallback if d_ws is too small: correct but slow (fp32 exact).
__global__ __launch_bounds__(256) void pd_naive(const float* __restrict__ x,
                                                const float* __restrict__ w,
                                                const float* __restrict__ bias,
                                                float* __restrict__ out) {
    const long long total = (long long)MROWS * PP * FOUT;
    for (long long idx = blockIdx.x * 256LL + threadIdx.x; idx < total;
         idx += (long long)gridDim.x * 256) {
        const int n = (int)(idx & 1023);
        const int p = (int)((idx >> 10) & 7);
        const long long m = idx >> 13;
        const float* xr = x + m * ROWSTRIDE + p * FIN;
        const float* wc = w + (size_t)p * (FIN*FOUT) + n;
        float s = bias[p * FOUT + n];
        for (int k = 0; k < FIN; ++k) s += xr[k] * wc[(size_t)k * FOUT];
        out[idx] = s;
    }
}

extern "C" void kernel_launch(void* const* d_in, const int* in_sizes, int n_in,
                              void* d_out, int out_size, void* d_ws, size_t ws_size,
                              hipStream_t stream) {
    const float* x    = (const float*)d_in[0];
    const float* w    = (const float*)d_in[1];
    const float* bias = (const float*)d_in[2];
    float* out = (float*)d_out;

    const size_t WT_BYTES = (size_t)PP * FIN * FOUT * 2;          // 16.8 MB
    const size_t XT_FULL  = (size_t)MROWS * PP * FIN * 2;         // 134.2 MB

    int nch = 1;
    while (nch <= 32 && WT_BYTES + XT_FULL / nch > ws_size) nch <<= 1;
    if (nch > 32) {
        pd_naive<<<dim3(2048), dim3(256), 0, stream>>>(x, w, bias, out);
        return;
    }

    unsigned short* wt = (unsigned short*)d_ws;
    unsigned short* xt = (unsigned short*)((char*)d_ws + WT_BYTES);
    const int Mc = MROWS / nch;
    const int MT = Mc / 256;

    wtrans<<<dim3(1024), dim3(256), 0, stream>>>(w, wt);
    for (int c = 0; c < nch; ++c) {
        const int m_base = c * Mc;
        xcvt<<<dim3(8 * MT * 4), dim3(256), 0, stream>>>(x, xt, m_base, MT);
        pd_gemm<<<dim3(8 * MT * 8), dim3(512), 0, stream>>>(xt, wt, bias, out, m_base, MT);
    }
}

// Round 8
// 271.697 us; speedup vs baseline: 1.1964x; 1.1269x over previous
//
#include <hip/hip_runtime.h>
#include <stdint.h>

// Problem constants
#define PP 8
#define FIN 1024
#define FOUT 1024
#define MROWS 8192
#define ROWSTRIDE 8192
#define OROWSTRIDE 8192

// Tile: 256x256, BK=64, 512 threads = 8 waves as 2(m) x 4(n); wave = 128x64
#define NKT 16

typedef float fx4 __attribute__((ext_vector_type(4)));
typedef short sv8 __attribute__((ext_vector_type(8)));
typedef short sv4 __attribute__((ext_vector_type(4)));

union BCvt4 { sv4 s; __bf16 b[4]; };

__device__ __forceinline__ unsigned short bfbits(float f) {
    union { __bf16 b; unsigned short u; } c; c.b = (__bf16)f; return c.u;
}

// ---------------------------------------------------------------------------
// Swizzled image format (A and B): row*128 + ((kg*16) ^ ((row&7)<<4)), kg=k/8
// ---------------------------------------------------------------------------

// Prepass 1 (verified r5-r7): W [P][K][N] fp32 -> Wt 16 KB tiles (p,nt128,kt)
__global__ __launch_bounds__(256) void wtrans(const float* __restrict__ w,
                                              unsigned short* __restrict__ wt) {
    __shared__ unsigned short L[64][132];
    const int bid = blockIdx.x;              // 1024
    const int p  = bid >> 7;
    const int nt = (bid >> 4) & 7;
    const int kt = bid & 15;
    const int k0 = kt * 64, n0 = nt * 128;
    const int t = threadIdx.x;

    const int nf = t & 31, kl = t >> 5;
#pragma unroll
    for (int rr = 0; rr < 8; ++rr) {
        const int k = rr * 8 + kl;
        fx4 v = *(const fx4*)(w + (size_t)p * (FIN*FOUT) + (size_t)(k0 + k) * FOUT + n0 + nf * 4);
        L[k][nf*4+0] = bfbits(v[0]); L[k][nf*4+1] = bfbits(v[1]);
        L[k][nf*4+2] = bfbits(v[2]); L[k][nf*4+3] = bfbits(v[3]);
    }
    __syncthreads();

    unsigned short* tile = wt + (size_t)bid * 8192;
    const int n = t & 127, khalf = t >> 7;
#pragma unroll
    for (int rr = 0; rr < 4; ++rr) {
        const int kg = khalf * 4 + rr;
        union { sv8 s; unsigned short us[8]; } u;
#pragma unroll
        for (int e = 0; e < 8; ++e) u.us[e] = L[kg * 8 + e][n];
        const int byte_ = n * 128 + ((kg * 16) ^ ((n & 7) << 4));
        *(sv8*)((char*)tile + byte_) = u.s;
    }
}

// Prepass 2 (verified r7): x fp32 -> xt 32 KB tiles (p, mt256, kt), coalesced
__global__ __launch_bounds__(256) void xcvt(const float* __restrict__ x,
                                            unsigned short* __restrict__ xt,
                                            int m_base, int MT) {
    const int bid = blockIdx.x;          // 8 * MT * 4
    const int p   = bid & 7;
    const int q   = bid >> 3;
    const int mt  = q >> 2;
    const int seg = q & 3;
    const int w   = threadIdx.x >> 6;
    const int l   = threadIdx.x & 63;

    char* tiles = (char*)xt + (size_t)((p * MT + mt) * 16) * 32768;
    const int ktl = l >> 4;
    const int kg  = (l & 15) >> 1;
    const int e8  = (l & 1) * 8;

#pragma unroll 2
    for (int i = 0; i < 16; ++i) {
        const int r = seg * 64 + w * 16 + i;
        const float* src = x + (size_t)(m_base + mt * 256 + r) * ROWSTRIDE + p * FIN;
        char* rowdst = tiles + r * 128 + ((kg * 16) ^ ((r & 7) << 4)) + e8;
#pragma unroll
        for (int rnd = 0; rnd < 4; ++rnd) {
            fx4 v = *(const fx4*)(src + rnd * 256 + l * 4);
            BCvt4 u;
            u.b[0] = (__bf16)v[0]; u.b[1] = (__bf16)v[1];
            u.b[2] = (__bf16)v[2]; u.b[3] = (__bf16)v[3];
            *(sv4*)(rowdst + (size_t)(rnd * 4 + ktl) * 32768) = u.s;
        }
    }
}

// ---------------------------------------------------------------------------
// 256x256 GEMM: A dbuf (stage t+1), B tri-buf (stage t+2), vmcnt(4)/tile.
// ---------------------------------------------------------------------------
#define STR2(x) #x
#define VMC(N) asm volatile("s_waitcnt vmcnt(" STR2(N) ")" ::: "memory")
#define MEMF asm volatile("" ::: "memory")
#define BARX do { MEMF; __builtin_amdgcn_s_barrier(); MEMF; } while (0)

// A: 32 KB tile = 4 gloads (512 thr x 16 B)
#define GLA4(skt, As) do {                                                     \
    const char* s_ = apanel + (size_t)(skt) * 32768 + tid * 16;                \
    char* d_ = (As) + tid * 16;                                                \
    _Pragma("unroll")                                                          \
    for (int c_ = 0; c_ < 4; ++c_)                                             \
        __builtin_amdgcn_global_load_lds(                                      \
            (const __attribute__((address_space(1))) void*)(s_ + c_ * 8192),   \
            (__attribute__((address_space(3))) void*)(d_ + c_ * 8192), 16, 0, 0); \
    MEMF;                                                                      \
} while (0)

// B half h: one 16 KB wt tile = 2 gloads; full B tile = GLB2(...,0)+GLB2(...,1)
#define GLB2(skt, Bs, h) do {                                                  \
    MEMF;                                                                      \
    const char* s_ = bpan + (size_t)((h) * 16 + (skt)) * 16384 + tid * 16;     \
    char* d_ = (Bs) + (h) * 16384 + tid * 16;                                  \
    _Pragma("unroll")                                                          \
    for (int c_ = 0; c_ < 2; ++c_)                                             \
        __builtin_amdgcn_global_load_lds(                                      \
            (const __attribute__((address_space(1))) void*)(s_ + c_ * 8192),   \
            (__attribute__((address_space(3))) void*)(d_ + c_ * 8192), 16, 0, 0); \
    MEMF;                                                                      \
} while (0)

// A frags: wave rows wm*128 + mh*64 + fi*16; 8 x ds_read_b128 into af
#define RDA(Ac, mh) do {                                                       \
    _Pragma("unroll")                                                          \
    for (int fi_ = 0; fi_ < 4; ++fi_) {                                        \
        const int row_ = wm * 128 + (mh) * 64 + fi_ * 16 + (lane & 15);        \
        const char* bp_ = (Ac) + row_ * 128;                                   \
        const int sw_ = (row_ & 7) << 4;                                       \
        _Pragma("unroll")                                                      \
        for (int ks_ = 0; ks_ < 2; ++ks_)                                      \
            af[fi_][ks_] = *(const sv8*)(bp_ + ((ks_ * 64 + (lane >> 4) * 16) ^ sw_)); \
    }                                                                          \
} while (0)

// B frags: rows wn*64 + nh*32 + j*16 in the 256-row image; 4 reads
#define RDB(Bc, nh, dst) do {                                                  \
    _Pragma("unroll")                                                          \
    for (int j_ = 0; j_ < 2; ++j_) {                                           \
        const int row_ = wn * 64 + (nh) * 32 + j_ * 16 + (lane & 15);          \
        const char* bp_ = (Bc) + row_ * 128;                                   \
        const int sw_ = (row_ & 7) << 4;                                       \
        _Pragma("unroll")                                                      \
        for (int ks_ = 0; ks_ < 2; ++ks_)                                      \
            dst[j_][ks_] = *(const sv8*)(bp_ + ((ks_ * 64 + (lane >> 4) * 16) ^ sw_)); \
    }                                                                          \
} while (0)

#define MQ(mh, nh, bfr) do {                                                   \
    __builtin_amdgcn_s_setprio(1);                                             \
    _Pragma("unroll")                                                          \
    for (int fi_ = 0; fi_ < 4; ++fi_)                                          \
        _Pragma("unroll")                                                      \
        for (int j_ = 0; j_ < 2; ++j_)                                         \
            _Pragma("unroll")                                                  \
            for (int ks_ = 0; ks_ < 2; ++ks_)                                  \
                acc[(mh)*4+fi_][(nh)*2+j_] = __builtin_amdgcn_mfma_f32_16x16x32_bf16( \
                    af[fi_][ks_], bfr[j_][ks_], acc[(mh)*4+fi_][(nh)*2+j_], 0, 0, 0); \
    __builtin_amdgcn_s_setprio(0);                                             \
} while (0)

// ENDW: 2 = vmcnt(4)+bar, 1 = vmcnt(0)+bar, 0 = none
#define TILE(Ac, Bc, An, Bn, skta, sktb, STA, STB, ENDW) do {                  \
    if (STA) GLA4(skta, An);                                                   \
    RDA(Ac, 0); RDB(Bc, 0, bf0);                                               \
    MQ(0, 0, bf0);                                                             \
    if (STB) GLB2(sktb, Bn, 0);                                                \
    RDB(Bc, 1, bf1);                                                           \
    MQ(0, 1, bf1);                                                             \
    if (STB) GLB2(sktb, Bn, 1);                                                \
    RDA(Ac, 1);                                                                \
    MQ(1, 1, bf1);                                                             \
    MQ(1, 0, bf0);                                                             \
    if ((ENDW) == 2) { VMC(4); BARX; }                                         \
    else if ((ENDW) == 1) { VMC(0); BARX; }                                    \
} while (0)

__global__ __launch_bounds__(512, 1)
void pd_gemm(const unsigned short* __restrict__ xt, const unsigned short* __restrict__ wtb,
             const float* __restrict__ bias, float* __restrict__ out,
             int m_base, int MT) {
    __shared__ __align__(16) char A0[32768];
    __shared__ __align__(16) char A1[32768];
    __shared__ __align__(16) char B0[32768];
    __shared__ __align__(16) char B1[32768];
    __shared__ __align__(16) char B2[32768];   // 160 KB total

    const int tid = threadIdx.x;
    const int lane = tid & 63;
    const int wv = tid >> 6;            // 8 waves: 2(m) x 4(n); wave = 128x64
    const int wm = wv >> 2, wn = wv & 3;

    // p == XCD; within p: n fastest (4 n-sharers of an A-panel co-timed)
    const int bid = blockIdx.x;
    const int p   = bid & 7;
    const int q   = bid >> 3;
    const int nt4 = q & 3;              // 256-col tile
    const int mt  = q >> 2;
    const int n0  = nt4 * 256;

    const char* apanel = (const char*)xt  + (size_t)((p * MT + mt) * 16) * 32768;
    const char* bpan   = (const char*)wtb + (size_t)(p * 8 + nt4 * 2) * 16 * 16384;

    fx4 acc[8][4];
#pragma unroll
    for (int i = 0; i < 8; ++i)
#pragma unroll
        for (int j = 0; j < 4; ++j) acc[i][j] = (fx4)0.0f;

    sv8 af[4][2], bf0[2][2], bf1[2][2];

    // Prologue: tile0 -> A0/B0, tile1 -> A1/B1 (16 loads).
    GLA4(0, A0); GLB2(0, B0, 0); GLB2(0, B0, 1);
    GLA4(1, A1); GLB2(1, B1, 0); GLB2(1, B1, 1);
    VMC(8);      // retire tile0's 8; tile1's 8 in flight
    BARX;

    // Tile 0 (special: A(1) already issued): stage B(2) only.
    // End: outstanding A(1)4+B(1)4+B(2)4 -> vmcnt(4) leaves B(2). ✓
    TILE(A0, B0, A1, B2, 1, 2, 0, 1, 2);

    // Steady tiles 1..12 (period 6). Entry invariant: B(t+1) 4 outstanding.
    // Body: +A(t+1) 4, +B(t+2) 4; vmcnt(4) retires B(t+1)+A(t+1). ✓
#pragma unroll 1
    for (int tb = 1; tb <= 7; tb += 6) {
        TILE(A1, B1, A0, B0, tb+1, tb+2, 1, 1, 2);   // t≡1
        TILE(A0, B2, A1, B1, tb+2, tb+3, 1, 1, 2);   // t≡2
        TILE(A1, B0, A0, B2, tb+3, tb+4, 1, 1, 2);   // t≡3
        TILE(A0, B1, A1, B0, tb+4, tb+5, 1, 1, 2);   // t≡4
        TILE(A1, B2, A0, B1, tb+5, tb+6, 1, 1, 2);   // t≡5
        TILE(A0, B0, A1, B2, tb+6, tb+7, 1, 1, 2);   // t≡0
    }
    TILE(A1, B1, A0, B0, 14, 15, 1, 1, 2);   // t=13
    TILE(A0, B2, A1, B0, 15,  0, 1, 0, 1);   // t=14: +A(15); vmcnt(0)
    TILE(A1, B0, A0, B0,  0,  0, 0, 0, 0);   // t=15

    // Epilogue: C/D map col = lane&15, row = (lane>>4)*4 + j (verified)
    const float* bs = bias + p * FOUT;
#pragma unroll
    for (int nf = 0; nf < 4; ++nf) {
        const int col = n0 + wn * 64 + nf * 16 + (lane & 15);
        const float bv = bs[col];
#pragma unroll
        for (int mf = 0; mf < 8; ++mf) {
            const int row = m_base + mt * 256 + wm * 128 + mf * 16 + (lane >> 4) * 4;
            float* o = out + (size_t)row * OROWSTRIDE + p * FOUT + col;
#pragma unroll
            for (int j = 0; j < 4; ++j)
                o[j * OROWSTRIDE] = acc[mf][nf][j] + bv;
        }
    }
}

// Fallback if d_ws too small: correct but slow (fp32 exact).
__global__ __launch_bounds__(256) void pd_naive(const float* __restrict__ x,
                                                const float* __restrict__ w,
                                                const float* __restrict__ bias,
                                                float* __restrict__ out) {
    const long long total = (long long)MROWS * PP * FOUT;
    for (long long idx = blockIdx.x * 256LL + threadIdx.x; idx < total;
         idx += (long long)gridDim.x * 256) {
        const int n = (int)(idx & 1023);
        const int p = (int)((idx >> 10) & 7);
        const long long m = idx >> 13;
        const float* xr = x + m * ROWSTRIDE + p * FIN;
        const float* wc = w + (size_t)p * (FIN*FOUT) + n;
        float s = bias[p * FOUT + n];
        for (int k = 0; k < FIN; ++k) s += xr[k] * wc[(size_t)k * FOUT];
        out[idx] = s;
    }
}

extern "C" void kernel_launch(void* const* d_in, const int* in_sizes, int n_in,
                              void* d_out, int out_size, void* d_ws, size_t ws_size,
                              hipStream_t stream) {
    const float* x    = (const float*)d_in[0];
    const float* w    = (const float*)d_in[1];
    const float* bias = (const float*)d_in[2];
    float* out = (float*)d_out;

    const size_t WT_BYTES = (size_t)PP * FIN * FOUT * 2;          // 16.8 MB
    const size_t XT_FULL  = (size_t)MROWS * PP * FIN * 2;         // 134.2 MB

    int nch = 1;
    while (nch <= 32 && WT_BYTES + XT_FULL / nch > ws_size) nch <<= 1;
    if (nch > 32) {
        pd_naive<<<dim3(2048), dim3(256), 0, stream>>>(x, w, bias, out);
        return;
    }

    unsigned short* wt = (unsigned short*)d_ws;
    unsigned short* xt = (unsigned short*)((char*)d_ws + WT_BYTES);
    const int Mc = MROWS / nch;
    const int MT = Mc / 256;

    wtrans<<<dim3(1024), dim3(256), 0, stream>>>(w, wt);
    for (int c = 0; c < nch; ++c) {
        const int m_base = c * Mc;
        xcvt<<<dim3(8 * MT * 4), dim3(256), 0, stream>>>(x, xt, m_base, MT);
        pd_gemm<<<dim3(8 * MT * 4), dim3(512), 0, stream>>>(xt, wt, bias, out, m_base, MT);
    }
}